// Round 9
// baseline (88.322 us; speedup 1.0000x reference)
//
#include <hip/hip_runtime.h>
#include <hip/hip_bf16.h>

#define NROWS 16384
#define DDIM  256
#define LOG2E 1.4426950408889634f
#define SCALE 7.213475204444817f   // (1/tau) * log2(e), tau = 0.2

typedef __attribute__((ext_vector_type(4))) float f32x4;
typedef __attribute__((ext_vector_type(2))) float f32x2;
typedef __attribute__((ext_vector_type(4))) int   i32x4;
typedef __attribute__((ext_vector_type(8))) int   i32x8;

#define UNIT_SCALE 0x7F7F7F7F   // e8m0 = 127 -> 2^0 = 1.0 in all 4 bytes

// ---------------------------------------------------------------------------
// Kernel 1: L2-normalize rows of z1,z2; quantize to OCP fp8 e4m3:
//   h1q = fp8(SCALE * h1_norm)   (A side, pre-scaled so exp2(acc) is direct)
//   h2q = fp8(h2_norm)           (B side)
// exact fp32 diag logits diag5[i] = 5 * cos(z1_i, z2_i); zero rowsum.
// ---------------------------------------------------------------------------
__global__ __launch_bounds__(256) void prep_kernel(
    const float* __restrict__ z1, const float* __restrict__ z2,
    unsigned char* __restrict__ h1q, unsigned char* __restrict__ h2q,
    float* __restrict__ diag5, float* __restrict__ rowsum) {
  int tid = threadIdx.x;
  int w = tid >> 6, lane = tid & 63;
  int r = blockIdx.x * 4 + w;

  const float4 a = ((const float4*)z1)[r * 64 + lane];
  const float4 b = ((const float4*)z2)[r * 64 + lane];

  float ss1 = a.x * a.x + a.y * a.y + a.z * a.z + a.w * a.w;
  float ss2 = b.x * b.x + b.y * b.y + b.z * b.z + b.w * b.w;
  float dp  = a.x * b.x + a.y * b.y + a.z * b.z + a.w * b.w;
  #pragma unroll
  for (int m = 1; m <= 32; m <<= 1) {
    ss1 += __shfl_xor(ss1, m);
    ss2 += __shfl_xor(ss2, m);
    dp  += __shfl_xor(dp, m);
  }
  float inv1 = 1.0f / fmaxf(sqrtf(ss1), 1e-12f);
  float inv2 = 1.0f / fmaxf(sqrtf(ss2), 1e-12f);
  float s1 = inv1 * SCALE;         // fold 1/tau*log2e into A

  int p1 = __builtin_amdgcn_cvt_pk_fp8_f32(a.x * s1, a.y * s1, 0, false);
  p1     = __builtin_amdgcn_cvt_pk_fp8_f32(a.z * s1, a.w * s1, p1, true);
  int p2 = __builtin_amdgcn_cvt_pk_fp8_f32(b.x * inv2, b.y * inv2, 0, false);
  p2     = __builtin_amdgcn_cvt_pk_fp8_f32(b.z * inv2, b.w * inv2, p2, true);
  ((int*)h1q)[r * 64 + lane] = p1;
  ((int*)h2q)[r * 64 + lane] = p2;

  if (lane == 0) diag5[r] = dp * inv1 * inv2 * 5.0f;
  if (tid < 4) rowsum[blockIdx.x * 4 + tid] = 0.0f;  // 4096 blocks * 4 = 16384
}

// ---------------------------------------------------------------------------
// Kernel 2: rowsum_i = sum_j exp2(h1q_i . h2q_j) via MX-scaled fp8 MFMA
// (mfma_scale_f32_16x16x128_f8f6f4, unit e8m0 scales -> exact fp8 matmul at
// 2x bf16 rate; MFMA floor 70K cyc/CU = 29.5us).
// VALU-cut (r7 showed VALUBusy 90K cyc > MFMA 70K, pipes serialized):
//  - swizzle XOR algebraically hoisted into per-lane bases pA/pB; all
//    ds_read offsets are compile-time immediates.
//  - stage uses FOUR per-lane global pointers bumped 16384/jt, offset imm = 0.
//    (r8 PITFALL: a nonzero imm offset on global_load_lds is applied to the
//    LDS destination too (LDS_ADDR = M0 + inst_offset + lane*size), so
//    offset:2048 scribbled the next wave's stripe and left rows 8..15
//    unwritten -> fp8-NaN garbage -> NaN loss. Never use imm offset here.)
//  - n-loop unrolled; rs accumulated as f32x2 (v_pk_add_f32).
// Block = 256 thr (4 waves), Mw=64 rows/wave, CSPL=16 -> 1024 blocks,
// 4 blocks/CU (LDS 4*32KB, VGPR<=128 -> 16 waves/CU).
// ---------------------------------------------------------------------------
#define CSPL 16
#define BN   64
#define NJT  ((NROWS / CSPL) / BN)   // 16 j-tiles per block

__global__ __launch_bounds__(256) void simexp_kernel(
    const unsigned char* __restrict__ h1q, const unsigned char* __restrict__ h2q,
    float* __restrict__ rowsum) {
  __shared__ alignas(16) unsigned char lds[2][BN * DDIM];   // 2 x 16 KB

  int tid = threadIdx.x, w = tid >> 6, lane = tid & 63;
  int bx = blockIdx.x;
  int rb = bx >> 4;        // row block 0..63 (256 rows each)
  int cs = bx & 15;        // column split 0..15 (cs, cs+8 share an XCD L2)
  int row0 = rb * 256 + w * 64;
  int c0 = cs * (NROWS / CSPL);

  const char* h1b = (const char*)h1q;
  const char* h2b = (const char*)h2q;

  // A fragments: 4 row-subtiles x 2 k128-steps, 32 fp8 each -> 64 VGPRs
  i32x8 afr[4][2];
  #pragma unroll
  for (int m = 0; m < 4; ++m)
    #pragma unroll
    for (int ks = 0; ks < 2; ++ks) {
      int row = row0 + m * 16 + (lane & 15);
      int off = row * 256 + ks * 128 + (lane >> 4) * 32;   // 32B aligned
      afr[m][ks] = *reinterpret_cast<const i32x8*>(h1b + off);
    }
  #pragma unroll
  for (int m = 0; m < 4; ++m)
    #pragma unroll
    for (int ks = 0; ks < 2; ++ks)
      asm volatile("" : "+v"(afr[m][ks]));   // keep resident

  // ---- hoisted LDS read bases (swizzle XOR folded per-lane) ----
  // original: addr = (row*256 + ks*128 + (lane>>4)*32 (+16 hi)) ^ ((row&7)<<4)
  // row = n*16 + (lane&15) -> row&7 = lane&7; the XOR touches only bits 4-6,
  // carried by (lane>>4)*32 and the +16; n*4096 and ks*128 stay additive.
  int sw  = (lane & 7) << 4;
  int pA  = (lane & 15) * 256 + (((lane >> 4) * 32) ^ sw);
  int pB  = (lane & 15) * 256 + ((((lane >> 4) * 32) + 16) ^ sw);

  // ---- hoisted stage pointers (4 loads, imm offset 0 -- see pitfall above) --
  // rit_i = w*16 + i*4 + (lane>>4); src = (c0 + jt*64 + rit)*256 + (kb ^ swz)
  int kb = (lane & 15) * 16;
  const char* P[4];
  #pragma unroll
  for (int i = 0; i < 4; ++i) {
    int rit = w * 16 + i * 4 + (lane >> 4);
    P[i] = h2b + (size_t)(c0 + rit) * 256 + (kb ^ ((rit & 7) << 4));
  }

  f32x2 rs2[4][2];
  #pragma unroll
  for (int m = 0; m < 4; ++m) {
    rs2[m][0] = (f32x2){0.f, 0.f};
    rs2[m][1] = (f32x2){0.f, 0.f};
  }

  // stage one 64x256 fp8 h2 tile (16 KB); advances P[] to the next tile
  auto stage = [&](int buf) {
    #pragma unroll
    for (int i = 0; i < 4; ++i) {
      __builtin_amdgcn_global_load_lds(
          (const __attribute__((address_space(1))) void*)P[i],
          (__attribute__((address_space(3))) void*)&lds[buf][w * 4096 + i * 1024],
          16, 0, 0);
      P[i] += 16384;
    }
  };

  stage(0);
  __syncthreads();

  for (int jt = 0; jt < NJT; ++jt) {
    int cur = jt & 1;
    if (jt + 1 < NJT) stage(cur ^ 1);

    const char* L = (const char*)&lds[cur][0];
    #pragma unroll
    for (int n = 0; n < 4; ++n) {
      f32x4 acc[4];
      #pragma unroll
      for (int m = 0; m < 4; ++m) acc[m] = (f32x4){0.f, 0.f, 0.f, 0.f};

      #pragma unroll
      for (int ks = 0; ks < 2; ++ks) {
        i32x4 lo = *reinterpret_cast<const i32x4*>(L + pA + (n * 4096 + ks * 128));
        i32x4 hi = *reinterpret_cast<const i32x4*>(L + pB + (n * 4096 + ks * 128));
        union { i32x8 v; i32x4 h[2]; } u;
        u.h[0] = lo; u.h[1] = hi;
        #pragma unroll
        for (int m = 0; m < 4; ++m)
          acc[m] = __builtin_amdgcn_mfma_scale_f32_16x16x128_f8f6f4(
              afr[m][ks], u.v, acc[m],
              0 /*cbsz: A=fp8*/, 0 /*blgp: B=fp8*/,
              0, UNIT_SCALE, 0, UNIT_SCALE);
      }
      // A pre-scaled by (1/tau)*log2e -> term = exp2(acc); pk-add pairs
      #pragma unroll
      for (int m = 0; m < 4; ++m) {
        rs2[m][0] += (f32x2){__builtin_amdgcn_exp2f(acc[m][0]),
                             __builtin_amdgcn_exp2f(acc[m][1])};
        rs2[m][1] += (f32x2){__builtin_amdgcn_exp2f(acc[m][2]),
                             __builtin_amdgcn_exp2f(acc[m][3])};
      }
    }
    __syncthreads();
  }

  // reduce the 16 column-lanes (lane&15) and add to global rowsum
  #pragma unroll
  for (int m = 0; m < 4; ++m)
    #pragma unroll
    for (int p = 0; p < 2; ++p)
      #pragma unroll
      for (int c = 0; c < 2; ++c) {
        float v = rs2[m][p][c];
        v += __shfl_xor(v, 1);
        v += __shfl_xor(v, 2);
        v += __shfl_xor(v, 4);
        v += __shfl_xor(v, 8);
        if ((lane & 15) == 0)
          atomicAdd(&rowsum[row0 + m * 16 + (lane >> 4) * 4 + p * 2 + c], v);
      }
}

// ---------------------------------------------------------------------------
// Kernel 3: loss = sum_i [ log(rowsum_i - exp(diag5_i)) - diag5_i ]
// ---------------------------------------------------------------------------
__global__ __launch_bounds__(1024) void loss_kernel(
    const float* __restrict__ rowsum, const float* __restrict__ diag5,
    float* __restrict__ out) {
  int tid = threadIdx.x;
  float s = 0.0f;
  for (int i = tid; i < NROWS; i += 1024) {
    float d5 = diag5[i];
    float de = __builtin_amdgcn_exp2f(d5 * LOG2E);
    s += logf(rowsum[i] - de) - d5;
  }
  #pragma unroll
  for (int m = 1; m <= 32; m <<= 1) s += __shfl_xor(s, m);
  __shared__ float wsum[16];
  if ((tid & 63) == 0) wsum[tid >> 6] = s;
  __syncthreads();
  if (tid == 0) {
    float t = 0.0f;
    #pragma unroll
    for (int i = 0; i < 16; ++i) t += wsum[i];
    out[0] = t;
  }
}

// ---------------------------------------------------------------------------
extern "C" void kernel_launch(void* const* d_in, const int* in_sizes, int n_in,
                              void* d_out, int out_size, void* d_ws, size_t ws_size,
                              hipStream_t stream) {
  const float* z1 = (const float*)d_in[0];
  const float* z2 = (const float*)d_in[1];

  char* ws = (char*)d_ws;
  unsigned char* h1q = (unsigned char*)(ws);             // 16384*256 = 4 MB
  unsigned char* h2q = (unsigned char*)(ws + 4194304);   // 4 MB
  float* diag5 = (float*)(ws + 8388608);                 // 64 KB
  float* rowsm = (float*)(ws + 8454144);                 // 64 KB
  if (ws_size < 8519680) return;                         // fail loudly

  prep_kernel<<<4096, 256, 0, stream>>>(z1, z2, h1q, h2q, diag5, rowsm);
  simexp_kernel<<<1024, 256, 0, stream>>>(h1q, h2q, rowsm);
  loss_kernel<<<1, 1024, 0, stream>>>(rowsm, diag5, (float*)d_out);
}